// Round 3
// baseline (415.522 us; speedup 1.0000x reference)
//
#include <hip/hip_runtime.h>
#include <hip/hip_bf16.h>

#define BB 64
#define SS 8192
#define DD 128
#define NCHUNK 8    // chunks per batch
#define CHROWS 1024 // rows per chunk
#define NTILE 16    // 64-row tiles per chunk

typedef __attribute__((ext_vector_type(8))) short bf16x8;
typedef __attribute__((ext_vector_type(4))) float f32x4;

// swizzled slot within a (w,kk) 128-slot region; 8-byte units
#define SWZ(c, qd) ((qd) * 16 + ((c) ^ (2 * (qd))))

__device__ __forceinline__ unsigned pk2(float x, float y) {
    __hip_bfloat162 h = __float22bfloat162_rn(make_float2(x, y));
    union { __hip_bfloat162 h2; unsigned u; } cv;
    cv.h2 = h;
    return cv.u;
}

__device__ __forceinline__ float bflo(unsigned p) { return __uint_as_float(p << 16); }
__device__ __forceinline__ float bfhi(unsigned p) { return __uint_as_float(p & 0xffff0000u); }

__device__ __forceinline__ float tanh_fast(float x) {
    float e = __expf(2.f * x);
    return 1.f - 2.f / (e + 1.f);
}

// ---------------- K1: q = tanh(input @ W_dec^T + b_dec)
__global__ void qproj_kernel(const float* __restrict__ input,
                             const float* __restrict__ W_dec,
                             const float* __restrict__ b_dec,
                             float* __restrict__ q) {
    __shared__ float xin[DD];
    const int b = blockIdx.x, d = threadIdx.x;  // 128 threads
    xin[d] = input[b * DD + d];
    __syncthreads();
    const float4* wrow = (const float4*)(W_dec + (size_t)d * DD);
    float acc = 0.f;
#pragma unroll
    for (int k4 = 0; k4 < DD / 4; k4++) {
        float4 w = wrow[k4];
        float4 x = ((const float4*)xin)[k4];
        acc += w.x * x.x + w.y * x.y + w.z * x.z + w.w * x.w;
    }
    q[b * DD + d] = tanh_fast(acc + b_dec[d]);
}

// ---------------- K2: fused scores + online softmax + weighted ctx sum
// Wave-independent main loop: each wave owns a private 16-row slice per
// tile (its own Cl region, its own online softmax + wc partial) -> ZERO
// __syncthreads() in the main loop. Waves free-run; each keeps 8KB of
// global loads in flight across its whole compute phase.
__global__ __launch_bounds__(256, 2) void score_fused_kernel(
    const float* __restrict__ ctx,
    const float* __restrict__ W_enc,
    const float* __restrict__ b_enc,
    const float* __restrict__ q,
    float* __restrict__ scores,
    float* __restrict__ wcp,   // [512][128]
    float* __restrict__ Mp,    // [512]
    float* __restrict__ Tp) {  // [512]
    __shared__ __align__(16) short Wl[16384];   // 32 KB fragment-order W_enc
    __shared__ __align__(16) short Cl[8192];    // 16 KB: 4 waves x 4KB private
    __shared__ float sw[64];                    // 4 waves x 16 private slots
    __shared__ float Mw[4], Tw[4];
    __shared__ float4 red[128];                 // 4 waves x 32

    const int t = threadIdx.x;

    // ---- stage W_enc: region (nt*4+kk), slot SWZ(col,qd), halves h=0/1
    const float4* W4 = (const float4*)W_enc;
    for (int c2 = t; c2 < 2048; c2 += 256) {
        int row = c2 >> 4, kc = c2 & 15;
        float4 f0 = W4[row * 32 + kc * 2];
        float4 f1 = W4[row * 32 + kc * 2 + 1];
        int nt = row >> 4, colw = row & 15, kk = kc >> 2, qd = kc & 3;
        int a8 = (nt * 4 + kk) * 128 + SWZ(colw, qd) * 2;
        uint4 u;
        u.x = pk2(f0.x, f0.y); u.y = pk2(f0.z, f0.w);
        u.z = pk2(f1.x, f1.y); u.w = pk2(f1.z, f1.w);
        *(uint4*)&Wl[a8 * 4] = u;
    }

    const int wv = t >> 6, lane = t & 63;
    const int col = lane & 15, quad = lane >> 4;
    const int b = blockIdx.x >> 3;
    const int chunk = blockIdx.x & 7;

    // per-lane piece coords for pack / weighted-sum
    const int u = lane & 31, rg = lane >> 5;
    const int ukk = u >> 3, uqd = (u >> 1) & 3, uh = u & 1;

    float qv[8], bv[8];
#pragma unroll
    for (int nt = 0; nt < 8; nt++) {
        qv[nt] = q[b * DD + nt * 16 + col];
        bv[nt] = b_enc[nt * 16 + col];
    }

    // wave's private row window: rows [wv*16, wv*16+16) of each 64-row tile
    const float4* base = (const float4*)(ctx
        + ((size_t)b * SS + (size_t)chunk * CHROWS + wv * 16) * DD);

    // prologue: load tile 0 (1KB contiguous per instruction per wave)
    float4 R[8];
#pragma unroll
    for (int i = 0; i < 8; i++) R[i] = base[(2 * i + rg) * 32 + u];

    __syncthreads();  // Wl ready

    float Mrun = -INFINITY, Trun = 0.f;
    float4 acc4 = {0.f, 0.f, 0.f, 0.f};

    for (int it = 0; it < NTILE; ++it) {
        // ---- pack R into the wave-private Cl region (rows c = 2i+rg)
#pragma unroll
        for (int i = 0; i < 8; i++) {
            int c = 2 * i + rg;
            int a8 = (wv * 4 + ukk) * 128 + SWZ(c, uqd) * 2 + uh;
            uint2 pk;
            pk.x = pk2(R[i].x, R[i].y);
            pk.y = pk2(R[i].z, R[i].w);
            *(uint2*)&Cl[a8 * 4] = pk;
        }

        // ---- issue next-tile loads (stay in flight across the compute)
        if (it < NTILE - 1) {
            const float4* nb = base + (size_t)(it + 1) * 2048;
#pragma unroll
            for (int i = 0; i < 8; i++) R[i] = nb[(2 * i + rg) * 32 + u];
        }

        // ---- A fragments from the wave-private region
        bf16x8 a[4];
#pragma unroll
        for (int kk = 0; kk < 4; kk++) {
            int a8 = (wv * 4 + kk) * 128 + SWZ(col, quad) * 2;
            a[kk] = *(const bf16x8*)&Cl[a8 * 4];
        }
        f32x4 acc[8];
#pragma unroll
        for (int nt = 0; nt < 8; nt++) {
            f32x4 c = {0.f, 0.f, 0.f, 0.f};
#pragma unroll
            for (int kk = 0; kk < 4; kk++) {
                int a8 = (nt * 4 + kk) * 128 + SWZ(col, quad) * 2;
                bf16x8 bf = *(const bf16x8*)&Wl[a8 * 4];
                c = __builtin_amdgcn_mfma_f32_16x16x32_bf16(a[kk], bf, c, 0, 0, 0);
            }
            acc[nt] = c;
        }

        // ---- epilogue: tanh, dot q, col-reduce -> row scores
        float vr[4];
#pragma unroll
        for (int r = 0; r < 4; r++) {
            float v = 0.f;
#pragma unroll
            for (int nt = 0; nt < 8; nt++)
                v += tanh_fast(acc[nt][r] + bv[nt]) * qv[nt];
            v += __shfl_xor(v, 1);
            v += __shfl_xor(v, 2);
            v += __shfl_xor(v, 4);
            v += __shfl_xor(v, 8);
            vr[r] = v;
        }
        // wave-private score exchange (same-wave DS ops are in order; no barrier)
        if (col == 0) {
#pragma unroll
            for (int r = 0; r < 4; r++) sw[wv * 16 + quad * 4 + r] = vr[r];
        }
        float sv = sw[wv * 16 + (lane & 15)];  // lane holds row (lane&15) score

        // ---- per-wave online softmax over this tile's 16 rows
        float m = sv;
        m = fmaxf(m, __shfl_xor(m, 1));
        m = fmaxf(m, __shfl_xor(m, 2));
        m = fmaxf(m, __shfl_xor(m, 4));
        m = fmaxf(m, __shfl_xor(m, 8));
        float Mnew = fmaxf(Mrun, m);
        float alpha = __expf(Mrun - Mnew);
        float wl = __expf(sv - Mnew);
        float ts = wl;
        ts += __shfl_xor(ts, 1);
        ts += __shfl_xor(ts, 2);
        ts += __shfl_xor(ts, 4);
        ts += __shfl_xor(ts, 8);
        Trun = Trun * alpha + ts;
        Mrun = Mnew;

        if (lane < 16)
            scores[(size_t)b * SS + (size_t)chunk * CHROWS + it * 64 + wv * 16 + lane] = sv;

        // ---- weighted ctx accumulation from the wave-private bf16 tile
        acc4.x *= alpha; acc4.y *= alpha; acc4.z *= alpha; acc4.w *= alpha;
#pragma unroll
        for (int i = 0; i < 8; i++) {
            int c = 2 * i + rg;
            int a8 = (wv * 4 + ukk) * 128 + SWZ(c, uqd) * 2 + uh;
            uint2 pk = *(const uint2*)&Cl[a8 * 4];
            float wi = __shfl(wl, c);
            acc4.x += wi * bflo(pk.x);
            acc4.y += wi * bfhi(pk.x);
            acc4.z += wi * bflo(pk.y);
            acc4.w += wi * bfhi(pk.y);
        }
        // next iteration's pack overwrites this region only after these reads
        // (same-wave program order) -> single buffer is safe
    }

    // ---- merge the 4 wave partials (one barrier total)
    acc4.x += __shfl_xor(acc4.x, 32);
    acc4.y += __shfl_xor(acc4.y, 32);
    acc4.z += __shfl_xor(acc4.z, 32);
    acc4.w += __shfl_xor(acc4.w, 32);
    if (lane < 32) red[wv * 32 + lane] = acc4;
    if (lane == 0) { Mw[wv] = Mrun; Tw[wv] = Trun; }
    __syncthreads();
    if (t < 32) {
        float M = fmaxf(fmaxf(Mw[0], Mw[1]), fmaxf(Mw[2], Mw[3]));
        float e0 = __expf(Mw[0] - M), e1 = __expf(Mw[1] - M);
        float e2 = __expf(Mw[2] - M), e3 = __expf(Mw[3] - M);
        float4 p0 = red[t], p1 = red[32 + t], p2 = red[64 + t], p3 = red[96 + t];
        float4 s;
        s.x = p0.x * e0 + p1.x * e1 + p2.x * e2 + p3.x * e3;
        s.y = p0.y * e0 + p1.y * e1 + p2.y * e2 + p3.y * e3;
        s.z = p0.z * e0 + p1.z * e1 + p2.z * e2 + p3.z * e3;
        s.w = p0.w * e0 + p1.w * e1 + p2.w * e2 + p3.w * e3;
        *(float4*)&wcp[(size_t)blockIdx.x * DD + 4 * t] = s;
        if (t == 0) {
            Mp[blockIdx.x] = M;
            Tp[blockIdx.x] = Tw[0] * e0 + Tw[1] * e1 + Tw[2] * e2 + Tw[3] * e3;
        }
    }
}

// ---------------- K3: combine 8 per-block partials per batch + fused out proj
__global__ void combine_out_kernel(const float* __restrict__ wcp,
                                   const float* __restrict__ Mp,
                                   const float* __restrict__ Tp,
                                   const float* __restrict__ q,
                                   const float* __restrict__ W_out,
                                   float* __restrict__ h,
                                   float* __restrict__ Ms,
                                   float* __restrict__ Tinv) {
    __shared__ float cat[2 * DD];
    const int b = blockIdx.x, d = threadIdx.x;  // 128 threads
    float M = -INFINITY;
#pragma unroll
    for (int j = 0; j < NCHUNK; j++) M = fmaxf(M, Mp[b * NCHUNK + j]);
    float T = 0.f, acc = 0.f;
#pragma unroll
    for (int j = 0; j < NCHUNK; j++) {
        float e = __expf(Mp[b * NCHUNK + j] - M);
        T += Tp[b * NCHUNK + j] * e;
        acc += wcp[(size_t)(b * NCHUNK + j) * DD + d] * e;
    }
    float ti = 1.f / T;
    cat[d] = acc * ti;          // weighted_context
    cat[DD + d] = q[b * DD + d];
    if (d == 0) { Ms[b] = M; Tinv[b] = ti; }
    __syncthreads();
    const float4* wrow = (const float4*)(W_out + (size_t)d * 2 * DD);
    float a2 = 0.f;
#pragma unroll
    for (int k4 = 0; k4 < 2 * DD / 4; k4++) {
        float4 w = wrow[k4];
        float4 x = ((const float4*)cat)[k4];
        a2 += w.x * x.x + w.y * x.y + w.z * x.z + w.w * x.w;
    }
    h[b * DD + d] = tanh_fast(a2);
}

// ---------------- K4: attn = exp(scores - M)/T
__global__ __launch_bounds__(512) void attnfin_kernel(const float* __restrict__ scores,
                                                      const float* __restrict__ Ms,
                                                      const float* __restrict__ Tinv,
                                                      float* __restrict__ attn) {
    const int b = blockIdx.x >> 2, seg = blockIdx.x & 3;
    const float M = Ms[b], ti = Tinv[b];
    const float4* s4 = (const float4*)(scores + (size_t)b * SS) + seg * 512;
    float4* a4 = (float4*)(attn + (size_t)b * SS) + seg * 512;
    float4 v = s4[threadIdx.x];
    v.x = __expf(v.x - M) * ti;
    v.y = __expf(v.y - M) * ti;
    v.z = __expf(v.z - M) * ti;
    v.w = __expf(v.w - M) * ti;
    a4[threadIdx.x] = v;
}

extern "C" void kernel_launch(void* const* d_in, const int* in_sizes, int n_in,
                              void* d_out, int out_size, void* d_ws, size_t ws_size,
                              hipStream_t stream) {
    const float* input = (const float*)d_in[0];
    const float* ctx   = (const float*)d_in[1];
    const float* W_enc = (const float*)d_in[2];
    const float* b_enc = (const float*)d_in[3];
    const float* W_dec = (const float*)d_in[4];
    const float* b_dec = (const float*)d_in[5];
    const float* W_out = (const float*)d_in[6];

    float* h    = (float*)d_out;            // [B, D]
    float* attn = (float*)d_out + BB * DD;  // [B, S]

    float* ws     = (float*)d_ws;
    float* q      = ws;                       // 8192
    float* scores = ws + 8192;                // 524288 raw scores
    float* wcp    = scores + 524288;          // 512*128 partials
    float* Mp     = wcp + 512 * DD;           // 512
    float* Tp     = Mp + 512;                 // 512
    float* Ms     = Tp + 512;                 // 64
    float* Tinv   = Ms + 64;                  // 64

    qproj_kernel<<<BB, DD, 0, stream>>>(input, W_dec, b_dec, q);
    score_fused_kernel<<<BB * NCHUNK, 256, 0, stream>>>(ctx, W_enc, b_enc, q,
                                                        scores, wcp, Mp, Tp);
    combine_out_kernel<<<BB, DD, 0, stream>>>(wcp, Mp, Tp, q, W_out, h, Ms, Tinv);
    attnfin_kernel<<<BB * 4, 512, 0, stream>>>(scores, Ms, Tinv, attn);
}